// Round 1
// baseline (279.181 us; speedup 1.0000x reference)
//
#include <hip/hip_runtime.h>
#include <hip/hip_bf16.h>
#include <cstddef>
#include <cstdint>

#define B_ 32
#define T_ 2048
#define D_ 512
#define U_ 512

typedef __attribute__((ext_vector_type(8))) short bf16x8;   // 8 bf16 = 4 VGPRs
typedef __attribute__((ext_vector_type(4))) float f32x4;    // MFMA 16x16 accum

__device__ __forceinline__ unsigned short f2bf(float f) {
  union { float f; unsigned u; } x; x.f = f;
  unsigned r = x.u + 0x7fffu + ((x.u >> 16) & 1u);  // RNE (off critical path)
  return (unsigned short)(r >> 16);
}
__device__ __forceinline__ float tanh_fast(float x) {
  float e = __expf(2.0f * x);
  return 1.0f - 2.0f * __builtin_amdgcn_rcpf(e + 1.0f);
}

#define AS1C(p) ((const __attribute__((address_space(1))) unsigned*)(p))
#define AS3(p)  ((__attribute__((address_space(3))) unsigned*)(p))

// ---------- kA: W2 pack via LDS (blocks 0..15, coalesced) + q_proj/zero-init (16..79) ----------
// Old pack: 262K scattered 4B loads (stride 2KB) -> ~64B line per 4B used. New: float4-coalesced
// read of a 32x512 W2 slab into LDS (bf16, +2 pad), then fully-coalesced W2P writes.
// Mapping identity vs old code: p = ut*4096 + kg*256 + tid  ->  l = tid>>2 (lq=tid>>6,
// lr=(tid>>2)&15), j = tid&3, u = ut*16+lr, k = kg*32 + lq*8 + 2j (+1 for hi half). Verified.
__global__ void kA_prep(const float* __restrict__ W2, unsigned* __restrict__ W2P,
                        const float* __restrict__ query, const float* __restrict__ W1,
                        const float* __restrict__ W1b, const float* __restrict__ W2b,
                        float* __restrict__ qp, float* __restrict__ score,
                        float* __restrict__ ctx) {
  const int tid = threadIdx.x;              // 256
  if (blockIdx.x < 16) {
    const int kg = blockIdx.x;              // K-group of 32 rows
    __shared__ unsigned short w2s[32][514]; // +2 pad breaks read-phase bank aliasing (32.9 KB)
    const float4* W2v = (const float4*)(W2 + (size_t)kg * 32 * U_);
    #pragma unroll
    for (int i = 0; i < 16; ++i) {
      int idx = i * 256 + tid;              // float4 index in 32x512 slab (128 per row)
      float4 v = W2v[idx];
      int r = idx >> 7, c = (idx & 127) * 4;
      w2s[r][c + 0] = f2bf(v.x); w2s[r][c + 1] = f2bf(v.y);
      w2s[r][c + 2] = f2bf(v.z); w2s[r][c + 3] = f2bf(v.w);
    }
    __syncthreads();
    const int lq = tid >> 6, lr = (tid >> 2) & 15, j = tid & 3;
    const int kb = lq * 8 + j * 2;
    #pragma unroll
    for (int ut = 0; ut < 32; ++ut)
      W2P[ut * 4096 + kg * 256 + tid] =
          (unsigned)w2s[kb][ut * 16 + lr] | ((unsigned)w2s[kb + 1][ut * 16 + lr] << 16);
  } else {
    __shared__ float qs[D_];
    const int blk = blockIdx.x - 16;        // 0..63
    const int b = blk >> 1, uhh = (blk & 1) * 256;
    qs[tid] = query[b * D_ + tid];
    qs[tid + 256] = query[b * D_ + tid + 256];
    __syncthreads();
    const int u = uhh + tid;
    float a0 = 0, a1 = 0, a2 = 0, a3 = 0, a4 = 0, a5 = 0, a6 = 0, a7 = 0;
    for (int d = 0; d < D_; d += 8) {
      a0 += qs[d + 0] * W1[(size_t)(d + 0) * U_ + u];
      a1 += qs[d + 1] * W1[(size_t)(d + 1) * U_ + u];
      a2 += qs[d + 2] * W1[(size_t)(d + 2) * U_ + u];
      a3 += qs[d + 3] * W1[(size_t)(d + 3) * U_ + u];
      a4 += qs[d + 4] * W1[(size_t)(d + 4) * U_ + u];
      a5 += qs[d + 5] * W1[(size_t)(d + 5) * U_ + u];
      a6 += qs[d + 6] * W1[(size_t)(d + 6) * U_ + u];
      a7 += qs[d + 7] * W1[(size_t)(d + 7) * U_ + u];
    }
    qp[b * U_ + u] = ((a0 + a1) + (a2 + a3)) + ((a4 + a5) + (a6 + a7)) + W1b[u] + W2b[u];
    const int gt = blk * 256 + tid;         // 0..16383
    ctx[gt] = 0.0f;
    #pragma unroll
    for (int i = 0; i < 4; ++i) score[i * 16384 + gt] = 0.0f;
  }
}

// ---------- k2: score[m] += sum_u tanh(values@W2 + qp) * Vw  (bf16 MFMA) ----------
// 64m x 256u-half blocks (grid 2048 = 4 exact rounds at 2 blocks/CU). v2 pipeline (T3+T4+T5):
//   * 4 LDS buffers (64 KB), values-eighth DMA'd 2 phases ahead via global_load_lds x16B.
//   * counted-vmcnt barriers replace __syncthreads: entering barrier e the per-wave FIFO is
//     {stage(e)[4], B(e)[8], stage(e+1)[4]} -> s_waitcnt vmcnt(12) drains exactly stage(e)
//     (vmcnt(8) at e=7). B-loads are issued BEFORE the stage-DMA each phase so the compiler's
//     own wait for B (vmcnt(16)) leaves both in-flight stages outstanding -- no forced drain.
//   * sched_barrier(0) fences pin all vmem/ds issue inside its phase (no cross-barrier motion).
//   * s_setprio(1) around each 16-MFMA cluster (pays once the schedule has wave role-split).
// XOR-swizzled fp32 A staging kept from v1 (verified: 0 bank conflicts).
__global__ __launch_bounds__(256, 2) void k2_dma(
    const float* __restrict__ values, const unsigned short* __restrict__ W2P,
    const float* __restrict__ qp, const float* __restrict__ Vw,
    float* __restrict__ score) {
  __shared__ float av[4][4096];             // 4 x 64 rows x 64 floats = 64 KB
  const int tid = threadIdx.x;
  const int bx = blockIdx.x;
  const int mt = bx >> 1, uh = bx & 1;      // block = m-tile x u-half
  const int m0 = mt * 64;                   // 2048%64==0: never crosses batch
  const int b = m0 >> 11;
  const int l = tid & 63, w = tid >> 6;
  const int lr = l & 15, lq = l >> 4;

  const int drow = l >> 4;
  const int dchunk = l & 15;

  f32x4 acc[4][4];                          // 64 acc regs (AGPR side)
  #pragma unroll
  for (int mi = 0; mi < 4; ++mi)
    #pragma unroll
    for (int ni = 0; ni < 4; ++ni) acc[mi][ni] = (f32x4){0.f, 0.f, 0.f, 0.f};

  // packed-B: u-tile = uh*16 + w*4 + ni; short offset = ut*8192 + kg*512 + l*8
  const unsigned short* Bb = W2P + (size_t)(uh * 16 + w * 4) * 8192 + (size_t)l * 8;

  auto stage = [&](int s) {                 // DMA K-eighth s into buffer s&3
    const int p = s & 3;
    #pragma unroll
    for (int j = 0; j < 4; ++j) {
      int g = w * 4 + j;
      int row = g * 4 + drow;               // 0..63 within m-tile
      int q = dchunk ^ (row & 15);          // swizzled source chunk
      const float* gp = values + (size_t)(m0 + row) * D_ + s * 64 + q * 4;
      __builtin_amdgcn_global_load_lds(AS1C(gp), AS3(&av[p][g * 256]), 16, 0, 0);
    }
  };

  bf16x8 Bf[2][8];                          // double-buffered B: [phase&1][kq*4+ni]
  auto loadB = [&](int ph) {                // 8 loads: both kgs of phase ph
    const int slot = ph & 1;
    #pragma unroll
    for (int kq = 0; kq < 2; ++kq)
      #pragma unroll
      for (int ni = 0; ni < 4; ++ni)
        Bf[slot][kq * 4 + ni] =
            *(const bf16x8*)(Bb + (size_t)ni * 8192 + (size_t)(2 * ph + kq) * 512);
  };

  // prologue issue order matters for the vmcnt FIFO audit: B0, st0, B1, st1.
  loadB(0);
  stage(0);
  loadB(1);
  stage(1);

  #pragma unroll
  for (int e = 0; e < 8; ++e) {             // 8 phases x 2 kg; K = 512
    __builtin_amdgcn_sched_barrier(0);
    if (e == 7) asm volatile("s_waitcnt vmcnt(8)" ::: "memory");
    else        asm volatile("s_waitcnt vmcnt(12)" ::: "memory");
    __builtin_amdgcn_s_barrier();
    __builtin_amdgcn_sched_barrier(0);
    if (e < 7) loadB(e + 1);                // B before stage: compiler's B-wait spares DMAs
    if (e < 6) stage(e + 2);

    #pragma unroll
    for (int kq = 0; kq < 2; ++kq) {
      bf16x8 a[4];
      #pragma unroll
      for (int mi = 0; mi < 4; ++mi) {
        const int row = mi * 16 + lr;
        const int p0 = (kq * 8 + lq * 2) ^ lr;        // swizzled position of chunk q0
        f32x4 flo = *(const f32x4*)&av[e & 3][row * 64 + (p0 << 2)];
        f32x4 fhi = *(const f32x4*)&av[e & 3][row * 64 + ((p0 ^ 1) << 2)];
        union { bf16x8 v; __hip_bfloat162 h[4]; } A;
        A.h[0] = __float22bfloat162_rn(make_float2(flo.x, flo.y));
        A.h[1] = __float22bfloat162_rn(make_float2(flo.z, flo.w));
        A.h[2] = __float22bfloat162_rn(make_float2(fhi.x, fhi.y));
        A.h[3] = __float22bfloat162_rn(make_float2(fhi.z, fhi.w));
        a[mi] = A.v;
      }
      __builtin_amdgcn_s_setprio(1);
      #pragma unroll
      for (int ni = 0; ni < 4; ++ni)
        #pragma unroll
        for (int mi = 0; mi < 4; ++mi)
          acc[mi][ni] = __builtin_amdgcn_mfma_f32_16x16x32_bf16(
              a[mi], Bf[e & 1][kq * 4 + ni], acc[mi][ni], 0, 0, 0);
      __builtin_amdgcn_s_setprio(0);
    }
  }

  // epilogue: tanh + weighted reduce over u (C/D: col=lane&15 -> u, row=lq*4+reg -> m)
  float sacc[4][4];
  #pragma unroll
  for (int mi = 0; mi < 4; ++mi)
    #pragma unroll
    for (int r = 0; r < 4; ++r) sacc[mi][r] = 0.0f;
  #pragma unroll
  for (int ni = 0; ni < 4; ++ni) {
    int u = uh * 256 + w * 64 + ni * 16 + lr;
    float qpv = qp[b * U_ + u], vv = Vw[u];
    #pragma unroll
    for (int mi = 0; mi < 4; ++mi)
      #pragma unroll
      for (int r = 0; r < 4; ++r)
        sacc[mi][r] += tanh_fast(acc[mi][ni][r] + qpv) * vv;
  }
  #pragma unroll
  for (int mi = 0; mi < 4; ++mi)
    #pragma unroll
    for (int r = 0; r < 4; ++r) {
      float v = sacc[mi][r];
      v += __shfl_xor(v, 1); v += __shfl_xor(v, 2);
      v += __shfl_xor(v, 4); v += __shfl_xor(v, 8);
      if (lr == 0) atomicAdd(&score[m0 + mi * 16 + lq * 4 + r], v);
    }
}

// ---------- k3: softmax over T per batch (in-place: score region == attn region) ----------
__global__ void k3_softmax(const float* __restrict__ score, float* __restrict__ attn) {
  __shared__ float red[8];
  const int b = blockIdx.x, tid = threadIdx.x;  // 32 blocks x 256
  const float* s = score + b * T_;
  float v[8];
  float mx = -1e30f;
  #pragma unroll
  for (int i = 0; i < 8; ++i) { v[i] = s[tid + i * 256]; mx = fmaxf(mx, v[i]); }
  #pragma unroll
  for (int off = 1; off < 64; off <<= 1) mx = fmaxf(mx, __shfl_xor(mx, off));
  if ((tid & 63) == 0) red[tid >> 6] = mx;
  __syncthreads();
  mx = fmaxf(fmaxf(red[0], red[1]), fmaxf(red[2], red[3]));
  float sum = 0.0f;
  #pragma unroll
  for (int i = 0; i < 8; ++i) { v[i] = __expf(v[i] - mx); sum += v[i]; }
  #pragma unroll
  for (int off = 1; off < 64; off <<= 1) sum += __shfl_xor(sum, off);
  if ((tid & 63) == 0) red[4 + (tid >> 6)] = sum;
  __syncthreads();
  sum = (red[4] + red[5]) + (red[6] + red[7]);
  float inv = 1.0f / sum;
  #pragma unroll
  for (int i = 0; i < 8; ++i) attn[b * T_ + tid + i * 256] = v[i] * inv;
}

// ---------- k4: context[b,:] = sum_t attn[b,t] * values[b,t,:] ----------
__global__ void k4_ctx(const float* __restrict__ values, const float* __restrict__ attn,
                       float* __restrict__ ctx) {
  __shared__ float at[64];
  __shared__ float ps[512];
  const int blk = blockIdx.x;               // 1024 = 32 b x 32 t-chunks of 64
  const int b = blk >> 5, tc = blk & 31;
  const int tid = threadIdx.x;              // 256
  if (tid < 64) at[tid] = attn[b * T_ + tc * 64 + tid];
  __syncthreads();
  const int q = tid & 127;
  const int r0 = tid >> 7;
  const float4* vb = (const float4*)(values + ((size_t)b * T_ + tc * 64) * D_);
  float ax = 0.f, ay = 0.f, az = 0.f, aw = 0.f;
  #pragma unroll 8
  for (int tt = 0; tt < 32; ++tt) {
    int row = tt * 2 + r0;
    float4 v = vb[(size_t)row * 128 + q];
    float a = at[row];
    ax += a * v.x; ay += a * v.y; az += a * v.z; aw += a * v.w;
  }
  if (r0 == 1) { ps[4 * q] = ax; ps[4 * q + 1] = ay; ps[4 * q + 2] = az; ps[4 * q + 3] = aw; }
  __syncthreads();
  if (r0 == 0) {
    atomicAdd(&ctx[b * D_ + 4 * q + 0], ax + ps[4 * q + 0]);
    atomicAdd(&ctx[b * D_ + 4 * q + 1], ay + ps[4 * q + 1]);
    atomicAdd(&ctx[b * D_ + 4 * q + 2], az + ps[4 * q + 2]);
    atomicAdd(&ctx[b * D_ + 4 * q + 3], aw + ps[4 * q + 3]);
  }
}

extern "C" void kernel_launch(void* const* d_in, const int* in_sizes, int n_in,
                              void* d_out, int out_size, void* d_ws, size_t ws_size,
                              hipStream_t stream) {
  const float* query = (const float*)d_in[0];
  const float* values = (const float*)d_in[1];
  const float* W1w = (const float*)d_in[2];
  const float* W1b = (const float*)d_in[3];
  const float* W2w = (const float*)d_in[4];
  const float* W2b = (const float*)d_in[5];
  const float* Vw  = (const float*)d_in[6];
  // V_b (d_in[7]) is a constant shift under softmax -> dropped.

  float* out = (float*)d_out;
  float* ctx  = out;                 // [B, D]    = 16384 floats
  float* attn = out + B_ * D_;       // [B, T, 1] = 65536 floats
  float* score = attn;               // raw scores in attn region; k3 softmaxes in place

  char* ws = (char*)d_ws;            // needs 576 KB
  unsigned* W2P = (unsigned*)ws;                             // 512 KB packed bf16 B
  float* qp    = (float*)(ws + 512 * 1024);                  // 64 KB

  kA_prep<<<80, 256, 0, stream>>>(W2w, W2P, query, W1w, W1b, W2b, qp, score, ctx);
  k2_dma<<<2048, 256, 0, stream>>>(values, (const unsigned short*)W2P, qp, Vw, score);
  k3_softmax<<<32, 256, 0, stream>>>(score, attn);
  k4_ctx<<<1024, 256, 0, stream>>>(values, attn, ctx);
}

// Round 3
// 274.902 us; speedup vs baseline: 1.0156x; 1.0156x over previous
//
#include <hip/hip_runtime.h>
#include <hip/hip_bf16.h>
#include <cstddef>
#include <cstdint>

#define B_ 32
#define T_ 2048
#define D_ 512
#define U_ 512

typedef __attribute__((ext_vector_type(8))) short bf16x8;   // 8 bf16 = 4 VGPRs
typedef __attribute__((ext_vector_type(4))) float f32x4;    // MFMA 16x16 accum

__device__ __forceinline__ unsigned short f2bf(float f) {
  union { float f; unsigned u; } x; x.f = f;
  unsigned r = x.u + 0x7fffu + ((x.u >> 16) & 1u);  // RNE
  return (unsigned short)(r >> 16);
}
__device__ __forceinline__ float tanh_fast(float x) {
  float e = __expf(2.0f * x);
  return 1.0f - 2.0f * __builtin_amdgcn_rcpf(e + 1.0f);
}

// C = sum |Vw| : tanh-bound => |score| <= C, so exp(s-C) in (0,1] -- softmax needs no
// global max pass. Computed IDENTICALLY (wave-0 only, fixed shfl order) in k2attn and
// kB_final => bit-identical C in both kernels, no storage/sync needed.
__device__ __forceinline__ void wave0_sumabs_vw(const float* __restrict__ Vw,
                                                float* Cs, int tid) {
  if (tid < 64) {
    float c = 0.f;
    #pragma unroll
    for (int i = 0; i < 8; ++i) c += fabsf(Vw[tid + i * 64]);
    c += __shfl_xor(c, 1);  c += __shfl_xor(c, 2);  c += __shfl_xor(c, 4);
    c += __shfl_xor(c, 8);  c += __shfl_xor(c, 16); c += __shfl_xor(c, 32);
    if (tid == 0) *Cs = c;
  }
}

// ---------- kA: W2 pack via LDS (blocks 0..15) + q_proj / ctx zero-init (16..79) ----------
__global__ void kA_prep(const float* __restrict__ W2, unsigned* __restrict__ W2P,
                        const float* __restrict__ query, const float* __restrict__ W1,
                        const float* __restrict__ W1b, const float* __restrict__ W2b,
                        float* __restrict__ qp, float* __restrict__ ctx) {
  const int tid = threadIdx.x;              // 256
  if (blockIdx.x < 16) {
    const int kg = blockIdx.x;              // K-group of 32 rows
    __shared__ unsigned short w2s[32][514]; // +2 pad (32.9 KB)
    const float4* W2v = (const float4*)(W2 + (size_t)kg * 32 * U_);
    #pragma unroll
    for (int i = 0; i < 16; ++i) {
      int idx = i * 256 + tid;              // float4 index in 32x512 slab
      float4 v = W2v[idx];
      int r = idx >> 7, c = (idx & 127) * 4;
      w2s[r][c + 0] = f2bf(v.x); w2s[r][c + 1] = f2bf(v.y);
      w2s[r][c + 2] = f2bf(v.z); w2s[r][c + 3] = f2bf(v.w);
    }
    __syncthreads();
    const int lq = tid >> 6, lr = (tid >> 2) & 15, j = tid & 3;
    const int kb = lq * 8 + j * 2;
    #pragma unroll
    for (int ut = 0; ut < 32; ++ut)
      W2P[ut * 4096 + kg * 256 + tid] =
          (unsigned)w2s[kb][ut * 16 + lr] | ((unsigned)w2s[kb + 1][ut * 16 + lr] << 16);
  } else {
    __shared__ float qs[D_];
    const int blk = blockIdx.x - 16;        // 0..63
    const int b = blk >> 1, uhh = (blk & 1) * 256;
    qs[tid] = query[b * D_ + tid];
    qs[tid + 256] = query[b * D_ + tid + 256];
    __syncthreads();
    const int u = uhh + tid;
    float a0 = 0, a1 = 0, a2 = 0, a3 = 0, a4 = 0, a5 = 0, a6 = 0, a7 = 0;
    for (int d = 0; d < D_; d += 8) {
      a0 += qs[d + 0] * W1[(size_t)(d + 0) * U_ + u];
      a1 += qs[d + 1] * W1[(size_t)(d + 1) * U_ + u];
      a2 += qs[d + 2] * W1[(size_t)(d + 2) * U_ + u];
      a3 += qs[d + 3] * W1[(size_t)(d + 3) * U_ + u];
      a4 += qs[d + 4] * W1[(size_t)(d + 4) * U_ + u];
      a5 += qs[d + 5] * W1[(size_t)(d + 5) * U_ + u];
      a6 += qs[d + 6] * W1[(size_t)(d + 6) * U_ + u];
      a7 += qs[d + 7] * W1[(size_t)(d + 7) * U_ + u];
    }
    qp[b * U_ + u] = ((a0 + a1) + (a2 + a3)) + ((a4 + a5) + (a6 + a7)) + W1b[u] + W2b[u];
    const int gt = blk * 256 + tid;         // 0..16383: zero ctx (= unnormalized ctx accum)
    ctx[gt] = 0.0f;
  }
}

// ---------- k2attn: full fused attention row-chunk kernel ----------
// Block = 32 t-rows x FULL U=512 (owns its complete scores -> fused softmax-free epilogue).
// 2048 blocks x 512 thr (8 waves x {2 mi} x {4 ni}), acc only 32 VGPR/wave.
// A staged as BF16 in LDS (reg-stage global->cvt once->swizzled ds_write): 4 buffers x 4 KB,
// read-side cvt eliminated (was 4x-redundant VALU), LDS 17.1 KB -> 4 blocks/CU possible.
// Raw s_barrier + lgkmcnt(0) per phase (no vmcnt drain: G/B loads are register-tracked,
// compiler inserts counted waits; gload(e+3) issued at phase e, consumed at e+1 ~2-phase cover).
// Swizzles verified at b64-write (4 lanes/bank = min) and b128-read (8 lanes/bank = min).
// Epilogue: tanh+Vw reduce -> raw scores + p=exp(s-C) -> unnormalized ctx accumulated from
// L2-warm values re-read. Eliminates former k3 softmax + k4 ctx kernels entirely.
__global__ __launch_bounds__(512, 4) void k2attn(
    const float* __restrict__ values, const unsigned short* __restrict__ W2P,
    const float* __restrict__ qp, const float* __restrict__ Vw,
    float* __restrict__ score, float* __restrict__ ctxU) {
  __shared__ __align__(16) float avb[4][1024];   // 4 x 4 KB bf16 A buffers (32 rows x 128 B)
  __shared__ float sred[8][32];
  __shared__ float ps2[32];
  __shared__ float Cs;

  const int tid = threadIdx.x;              // 512
  const int bx = blockIdx.x;                // 2048 = 64 chunks x 32 batches
  const int m0 = bx * 32;                   // flat row (b*2048 + t), chunks never cross batch
  const int b = m0 >> 11;
  const int l = tid & 63, w = tid >> 6;     // 8 waves
  const int lr = l & 15, lq = l >> 4;

  // staging role: wave w stages rows w*4..w*4+3; lane covers 4 floats of k
  const int row_st = w * 4 + (l >> 4);
  const int fseg = l & 15;                  // k = fseg*4 .. +3 within the eighth
  const float* vrow = values + (size_t)(m0 + row_st) * D_ + fseg * 4;

  f32x4 acc[2][4];
  #pragma unroll
  for (int mi = 0; mi < 2; ++mi)
    #pragma unroll
    for (int ni = 0; ni < 4; ++ni) acc[mi][ni] = (f32x4){0.f, 0.f, 0.f, 0.f};

  const unsigned short* Bb = W2P + (size_t)(w * 4) * 8192 + (size_t)l * 8;

  // convert lane's 4 fp32 -> 4 bf16, swizzled ds_write_b64 (slot ^= row&7; bijective in-row)
  auto consume = [&](float4 g, int s) {
    __hip_bfloat162 h0 = __float22bfloat162_rn(make_float2(g.x, g.y));
    __hip_bfloat162 h1 = __float22bfloat162_rn(make_float2(g.z, g.w));
    union { __hip_bfloat162 h; unsigned u; } c0, c1; c0.h = h0; c1.h = h1;
    int slot = (fseg >> 1) ^ (row_st & 7);
    char* dst = (char*)avb[s & 3] + row_st * 128 + (slot << 4) + ((fseg & 1) << 3);
    *(uint2*)dst = make_uint2(c0.u, c1.u);
  };

  wave0_sumabs_vw(Vw, &Cs, tid);

  // prologue: issue 3 eighths, materialize 0 and 1
  float4 Ga = *(const float4*)(vrow);
  float4 Gb = *(const float4*)(vrow + 64);
  float4 Gc = *(const float4*)(vrow + 128);
  consume(Ga, 0);
  consume(Gb, 1);
  __syncthreads();                          // drains + publishes buf0/buf1 + Cs
  const float C = Cs;
  float4 Gcons = Gc;                        // eighth 2, written to buf2 during phase 0

  #pragma unroll
  for (int e = 0; e < 8; ++e) {             // K = 512 = 8 eighths x (2 x K32)
    float4 Gnew = (float4){0.f, 0.f, 0.f, 0.f};
    if (e < 5) Gnew = *(const float4*)(vrow + (e + 3) * 64);   // issue early: ~2-phase cover
    const char* buf = (const char*)avb[e & 3];
    #pragma unroll
    for (int kq = 0; kq < 2; ++kq) {
      const int kg = e * 2 + kq;
      const int sl = ((kq << 2) | lq) ^ (lr & 7);  // swizzled 16B slot (same for both mi)
      bf16x8 a0 = *(const bf16x8*)(buf + (lr) * 128 + (sl << 4));
      bf16x8 a1 = *(const bf16x8*)(buf + (16 + lr) * 128 + (sl << 4));
      bf16x8 b0 = *(const bf16x8*)(Bb + 0 * 8192 + (size_t)kg * 512);
      bf16x8 b1 = *(const bf16x8*)(Bb + 1 * 8192 + (size_t)kg * 512);
      bf16x8 b2 = *(const bf16x8*)(Bb + 2 * 8192 + (size_t)kg * 512);
      bf16x8 b3 = *(const bf16x8*)(Bb + 3 * 8192 + (size_t)kg * 512);
      __builtin_amdgcn_s_setprio(1);
      acc[0][0] = __builtin_amdgcn_mfma_f32_16x16x32_bf16(a0, b0, acc[0][0], 0, 0, 0);
      acc[1][0] = __builtin_amdgcn_mfma_f32_16x16x32_bf16(a1, b0, acc[1][0], 0, 0, 0);
      acc[0][1] = __builtin_amdgcn_mfma_f32_16x16x32_bf16(a0, b1, acc[0][1], 0, 0, 0);
      acc[1][1] = __builtin_amdgcn_mfma_f32_16x16x32_bf16(a1, b1, acc[1][1], 0, 0, 0);
      acc[0][2] = __builtin_amdgcn_mfma_f32_16x16x32_bf16(a0, b2, acc[0][2], 0, 0, 0);
      acc[1][2] = __builtin_amdgcn_mfma_f32_16x16x32_bf16(a1, b2, acc[1][2], 0, 0, 0);
      acc[0][3] = __builtin_amdgcn_mfma_f32_16x16x32_bf16(a0, b3, acc[0][3], 0, 0, 0);
      acc[1][3] = __builtin_amdgcn_mfma_f32_16x16x32_bf16(a1, b3, acc[1][3], 0, 0, 0);
      __builtin_amdgcn_s_setprio(0);
      if (kq == 0 && e < 6) consume(Gcons, e + 2);   // write buf[(e+2)&3]; its readers are
    }                                                 // 2 barriers away (safe), prev readers
    Gcons = Gnew;                                     // finished before barrier e-1.
    __builtin_amdgcn_sched_barrier(0);
    asm volatile("s_waitcnt lgkmcnt(0)" ::: "memory"); // drain my ds_write (NOT vmcnt!)
    __builtin_amdgcn_s_barrier();
    __builtin_amdgcn_sched_barrier(0);
  }

  // ---- epilogue 1: tanh + Vw-weighted reduce over u ----
  float sacc[2][4];
  #pragma unroll
  for (int mi = 0; mi < 2; ++mi)
    #pragma unroll
    for (int r = 0; r < 4; ++r) sacc[mi][r] = 0.0f;
  #pragma unroll
  for (int ni = 0; ni < 4; ++ni) {
    int u = (w * 4 + ni) * 16 + lr;
    float qpv = qp[b * U_ + u], vv = Vw[u];
    #pragma unroll
    for (int mi = 0; mi < 2; ++mi)
      #pragma unroll
      for (int r = 0; r < 4; ++r)
        sacc[mi][r] += tanh_fast(acc[mi][ni][r] + qpv) * vv;
  }
  #pragma unroll
  for (int mi = 0; mi < 2; ++mi)
    #pragma unroll
    for (int r = 0; r < 4; ++r) {
      float v = sacc[mi][r];
      v += __shfl_xor(v, 1); v += __shfl_xor(v, 2);
      v += __shfl_xor(v, 4); v += __shfl_xor(v, 8);
      if (lr == 0) sred[w][mi * 16 + lq * 4 + r] = v;
    }
  __syncthreads();

  // ---- epilogue 2: raw scores + p = exp(s - C) ----
  if (tid < 32) {
    float s = 0.f;
    #pragma unroll
    for (int wv = 0; wv < 8; ++wv) s += sred[wv][tid];
    score[m0 + tid] = s;                    // raw score (kB normalizes in place)
    ps2[tid] = __expf(s - C);
  }
  __syncthreads();

  // ---- epilogue 3: unnormalized context from L2-warm values rows ----
  float accc = 0.f;
  const int col = tid;                      // 512 threads <-> 512 cols
  #pragma unroll 4
  for (int row = 0; row < 32; ++row)
    accc += ps2[row] * values[(size_t)(m0 + row) * D_ + col];
  atomicAdd(&ctxU[(size_t)b * D_ + col], accc);
}

// ---------- kB: normalize (replaces softmax + ctx kernels) ----------
__global__ void kB_final(const float* __restrict__ Vw, float* __restrict__ attn,
                         float* __restrict__ ctx) {
  __shared__ float Cs;
  __shared__ float red[4];
  const int b = blockIdx.x, tid = threadIdx.x;  // 32 blocks x 256
  wave0_sumabs_vw(Vw, &Cs, tid);
  __syncthreads();
  const float C = Cs;
  float* s = attn + b * T_;
  float p[8];
  float sum = 0.f;
  #pragma unroll
  for (int i = 0; i < 8; ++i) { p[i] = __expf(s[tid + i * 256] - C); sum += p[i]; }
  #pragma unroll
  for (int off = 1; off < 64; off <<= 1) sum += __shfl_xor(sum, off);
  if ((tid & 63) == 0) red[tid >> 6] = sum;
  __syncthreads();
  sum = (red[0] + red[1]) + (red[2] + red[3]);
  const float inv = 1.0f / sum;
  #pragma unroll
  for (int i = 0; i < 8; ++i) attn[b * T_ + tid + i * 256] = p[i] * inv;
  #pragma unroll
  for (int i = 0; i < 2; ++i) ctx[b * D_ + tid + i * 256] *= inv;
}

extern "C" void kernel_launch(void* const* d_in, const int* in_sizes, int n_in,
                              void* d_out, int out_size, void* d_ws, size_t ws_size,
                              hipStream_t stream) {
  const float* query = (const float*)d_in[0];
  const float* values = (const float*)d_in[1];
  const float* W1w = (const float*)d_in[2];
  const float* W1b = (const float*)d_in[3];
  const float* W2w = (const float*)d_in[4];
  const float* W2b = (const float*)d_in[5];
  const float* Vw  = (const float*)d_in[6];
  // V_b (d_in[7]) is a constant shift under softmax -> dropped.

  float* out = (float*)d_out;
  float* ctx  = out;                 // [B, D]: holds unnormalized ctx until kB scales in place
  float* attn = out + B_ * D_;       // [B, T, 1]: holds raw scores until kB softmaxes in place
  float* score = attn;

  char* ws = (char*)d_ws;            // needs 576 KB (unchanged)
  unsigned* W2P = (unsigned*)ws;                             // 512 KB packed bf16 B
  float* qp    = (float*)(ws + 512 * 1024);                  // 64 KB

  kA_prep<<<80, 256, 0, stream>>>(W2w, W2P, query, W1w, W1b, W2b, qp, ctx);
  k2attn<<<2048, 512, 0, stream>>>(values, (const unsigned short*)W2P, qp, Vw, score, ctx);
  kB_final<<<32, 256, 0, stream>>>(Vw, attn, ctx);
}

// Round 4
// 267.391 us; speedup vs baseline: 1.0441x; 1.0281x over previous
//
#include <hip/hip_runtime.h>
#include <hip/hip_bf16.h>
#include <cstddef>
#include <cstdint>

#define B_ 32
#define T_ 2048
#define D_ 512
#define U_ 512

typedef __attribute__((ext_vector_type(8))) short bf16x8;   // 8 bf16 = 4 VGPRs
typedef __attribute__((ext_vector_type(4))) float f32x4;    // MFMA 16x16 accum

__device__ __forceinline__ unsigned short f2bf(float f) {
  union { float f; unsigned u; } x; x.f = f;
  unsigned r = x.u + 0x7fffu + ((x.u >> 16) & 1u);  // RNE
  return (unsigned short)(r >> 16);
}
__device__ __forceinline__ float tanh_fast(float x) {
  float e = __expf(2.0f * x);
  return 1.0f - 2.0f * __builtin_amdgcn_rcpf(e + 1.0f);
}

// C = sum |Vw| : tanh-bound => |score| <= C, so exp(s-C) in (0,1] -- softmax needs no
// global max pass. Computed IDENTICALLY (wave-0 only, fixed shfl order) in k2attn and
// kB_final => bit-identical C in both kernels, no storage/sync needed.
__device__ __forceinline__ void wave0_sumabs_vw(const float* __restrict__ Vw,
                                                float* Cs, int tid) {
  if (tid < 64) {
    float c = 0.f;
    #pragma unroll
    for (int i = 0; i < 8; ++i) c += fabsf(Vw[tid + i * 64]);
    c += __shfl_xor(c, 1);  c += __shfl_xor(c, 2);  c += __shfl_xor(c, 4);
    c += __shfl_xor(c, 8);  c += __shfl_xor(c, 16); c += __shfl_xor(c, 32);
    if (tid == 0) *Cs = c;
  }
}

// ---------- kA: W2 pack via LDS (blocks 0..15) + q_proj / ctx zero-init (16..79) ----------
__global__ void kA_prep(const float* __restrict__ W2, unsigned* __restrict__ W2P,
                        const float* __restrict__ query, const float* __restrict__ W1,
                        const float* __restrict__ W1b, const float* __restrict__ W2b,
                        float* __restrict__ qp, float* __restrict__ ctx) {
  const int tid = threadIdx.x;              // 256
  if (blockIdx.x < 16) {
    const int kg = blockIdx.x;              // K-group of 32 rows
    __shared__ unsigned short w2s[32][514]; // +2 pad (32.9 KB)
    const float4* W2v = (const float4*)(W2 + (size_t)kg * 32 * U_);
    #pragma unroll
    for (int i = 0; i < 16; ++i) {
      int idx = i * 256 + tid;              // float4 index in 32x512 slab
      float4 v = W2v[idx];
      int r = idx >> 7, c = (idx & 127) * 4;
      w2s[r][c + 0] = f2bf(v.x); w2s[r][c + 1] = f2bf(v.y);
      w2s[r][c + 2] = f2bf(v.z); w2s[r][c + 3] = f2bf(v.w);
    }
    __syncthreads();
    const int lq = tid >> 6, lr = (tid >> 2) & 15, j = tid & 3;
    const int kb = lq * 8 + j * 2;
    #pragma unroll
    for (int ut = 0; ut < 32; ++ut)
      W2P[ut * 4096 + kg * 256 + tid] =
          (unsigned)w2s[kb][ut * 16 + lr] | ((unsigned)w2s[kb + 1][ut * 16 + lr] << 16);
  } else {
    __shared__ float qs[D_];
    const int blk = blockIdx.x - 16;        // 0..63
    const int b = blk >> 1, uhh = (blk & 1) * 256;
    qs[tid] = query[b * D_ + tid];
    qs[tid + 256] = query[b * D_ + tid + 256];
    __syncthreads();
    const int u = uhh + tid;
    float a0 = 0, a1 = 0, a2 = 0, a3 = 0, a4 = 0, a5 = 0, a6 = 0, a7 = 0;
    for (int d = 0; d < D_; d += 8) {
      a0 += qs[d + 0] * W1[(size_t)(d + 0) * U_ + u];
      a1 += qs[d + 1] * W1[(size_t)(d + 1) * U_ + u];
      a2 += qs[d + 2] * W1[(size_t)(d + 2) * U_ + u];
      a3 += qs[d + 3] * W1[(size_t)(d + 3) * U_ + u];
      a4 += qs[d + 4] * W1[(size_t)(d + 4) * U_ + u];
      a5 += qs[d + 5] * W1[(size_t)(d + 5) * U_ + u];
      a6 += qs[d + 6] * W1[(size_t)(d + 6) * U_ + u];
      a7 += qs[d + 7] * W1[(size_t)(d + 7) * U_ + u];
    }
    qp[b * U_ + u] = ((a0 + a1) + (a2 + a3)) + ((a4 + a5) + (a6 + a7)) + W1b[u] + W2b[u];
    const int gt = blk * 256 + tid;         // 0..16383: zero ctx (= unnormalized ctx accum)
    ctx[gt] = 0.0f;
  }
}

// ---------- k2attn: fused attention row-chunk kernel, v4 pipeline ----------
// Block = 32 t-rows x FULL U=512; 2048 blocks x 512 thr (8 waves x {2 mi} x {4 ni}).
// vs R3 (106.9 us, every pipe idle -> per-phase B-load L2 stall + per-phase barrier lockstep):
//   * B ring-prefetch depth 3 (Bf[3][4], static idx under full unroll): frag for kq-step k
//     issued at k-2 (~200+ cy cover ~= L2 latency).  [was: loaded right before its MFMAs]
//   * values reg-pipeline depth 3: G(e+4) issued at phase e, consumed at e+2 (~2.2-phase cover).
//   * barrier every 2 phases (4 in main loop, was 8). Audit: with 4 LDS buffers, write(e)->
//     buf[(e+2)&3] vs prior readers (phase e-2) and vs consumers (phase e+2) always has >=1
//     lgkm-drained barrier between, incl. the 1-phase intra-interval wave drift.
// A staged bf16 (reg->cvt once->swizzled ds_write, both LDS phases at min bank aliasing,
// counters: 0 conflicts). Epilogue unchanged from R3 (HW-verified, absmax 4.9e-4).
__global__ __launch_bounds__(512, 4) void k2attn(
    const float* __restrict__ values, const unsigned short* __restrict__ W2P,
    const float* __restrict__ qp, const float* __restrict__ Vw,
    float* __restrict__ score, float* __restrict__ ctxU) {
  __shared__ __align__(16) float avb[4][1024];   // 4 x 4 KB bf16 A buffers (32 rows x 128 B)
  __shared__ float sred[8][32];
  __shared__ float ps2[32];
  __shared__ float Cs;

  const int tid = threadIdx.x;              // 512
  const int bx = blockIdx.x;                // 2048 = 64 chunks x 32 batches
  const int m0 = bx * 32;                   // flat row (b*2048 + t), chunks never cross batch
  const int b = m0 >> 11;
  const int l = tid & 63, w = tid >> 6;     // 8 waves
  const int lr = l & 15, lq = l >> 4;

  // staging role: wave w stages rows w*4..w*4+3; lane covers 4 floats of k
  const int row_st = w * 4 + (l >> 4);
  const int fseg = l & 15;                  // k = fseg*4 .. +3 within the eighth
  const float* vrow = values + (size_t)(m0 + row_st) * D_ + fseg * 4;

  f32x4 acc[2][4];
  #pragma unroll
  for (int mi = 0; mi < 2; ++mi)
    #pragma unroll
    for (int ni = 0; ni < 4; ++ni) acc[mi][ni] = (f32x4){0.f, 0.f, 0.f, 0.f};

  const unsigned short* Bb = W2P + (size_t)(w * 4) * 8192 + (size_t)l * 8;

  // convert lane's 4 fp32 -> 4 bf16, swizzled ds_write_b64 (slot ^= row&7; bijective in-row)
  auto consume = [&](float4 g, int s) {
    __hip_bfloat162 h0 = __float22bfloat162_rn(make_float2(g.x, g.y));
    __hip_bfloat162 h1 = __float22bfloat162_rn(make_float2(g.z, g.w));
    union { __hip_bfloat162 h; unsigned u; } c0, c1; c0.h = h0; c1.h = h1;
    int slot = (fseg >> 1) ^ (row_st & 7);
    char* dst = (char*)avb[s & 3] + row_st * 128 + (slot << 4) + ((fseg & 1) << 3);
    *(uint2*)dst = make_uint2(c0.u, c1.u);
  };

  bf16x8 Bf[3][4];                          // B ring: kq-step kappa lives in Bf[kappa%3]
  auto loadB = [&](int slot, int kappa) {
    #pragma unroll
    for (int ni = 0; ni < 4; ++ni)
      Bf[slot][ni] = *(const bf16x8*)(Bb + (size_t)ni * 8192 + (size_t)kappa * 512);
  };

  wave0_sumabs_vw(Vw, &Cs, tid);

  // prologue: issue 4 eighths + 2 B steps; materialize buf0/buf1
  float4 g0 = *(const float4*)(vrow);
  float4 g1 = *(const float4*)(vrow + 64);
  float4 g2 = *(const float4*)(vrow + 128);
  float4 g3 = *(const float4*)(vrow + 192);
  loadB(0, 0);
  loadB(1, 1);
  consume(g0, 0);
  consume(g1, 1);
  __syncthreads();                          // drains writes + publishes buf0/buf1 + Cs
  const float C = Cs;
  float4 Gpend[2];                          // entering phase e: Gpend = {G(e+2), G(e+3)}
  Gpend[0] = g2; Gpend[1] = g3;

  #pragma unroll
  for (int e = 0; e < 8; ++e) {             // K = 512 = 8 eighths x (2 x K32)
    float4 Gnew = (float4){0.f, 0.f, 0.f, 0.f};
    if (e < 4) Gnew = *(const float4*)(vrow + (e + 4) * 64);   // ~2.2-phase cover
    const char* buf = (const char*)avb[e & 3];
    #pragma unroll
    for (int kq = 0; kq < 2; ++kq) {
      const int kappa = e * 2 + kq;
      if (kappa + 2 < 16) loadB((kappa + 2) % 3, kappa + 2);   // ring prefetch, 2-step cover
      const int sl = ((kq << 2) | lq) ^ (lr & 7);  // swizzled 16B slot (same for both mi)
      bf16x8 a0 = *(const bf16x8*)(buf + (lr) * 128 + (sl << 4));
      bf16x8 a1 = *(const bf16x8*)(buf + (16 + lr) * 128 + (sl << 4));
      __builtin_amdgcn_s_setprio(1);
      acc[0][0] = __builtin_amdgcn_mfma_f32_16x16x32_bf16(a0, Bf[kappa % 3][0], acc[0][0], 0, 0, 0);
      acc[1][0] = __builtin_amdgcn_mfma_f32_16x16x32_bf16(a1, Bf[kappa % 3][0], acc[1][0], 0, 0, 0);
      acc[0][1] = __builtin_amdgcn_mfma_f32_16x16x32_bf16(a0, Bf[kappa % 3][1], acc[0][1], 0, 0, 0);
      acc[1][1] = __builtin_amdgcn_mfma_f32_16x16x32_bf16(a1, Bf[kappa % 3][1], acc[1][1], 0, 0, 0);
      acc[0][2] = __builtin_amdgcn_mfma_f32_16x16x32_bf16(a0, Bf[kappa % 3][2], acc[0][2], 0, 0, 0);
      acc[1][2] = __builtin_amdgcn_mfma_f32_16x16x32_bf16(a1, Bf[kappa % 3][2], acc[1][2], 0, 0, 0);
      acc[0][3] = __builtin_amdgcn_mfma_f32_16x16x32_bf16(a0, Bf[kappa % 3][3], acc[0][3], 0, 0, 0);
      acc[1][3] = __builtin_amdgcn_mfma_f32_16x16x32_bf16(a1, Bf[kappa % 3][3], acc[1][3], 0, 0, 0);
      __builtin_amdgcn_s_setprio(0);
      if (kq == 0 && e < 6) consume(Gpend[0], e + 2);  // write buf[(e+2)&3]
    }
    Gpend[0] = Gpend[1]; Gpend[1] = Gnew;
    if (e & 1) {                            // barrier every 2 phases (4-buffer slack audit ok)
      __builtin_amdgcn_sched_barrier(0);
      asm volatile("s_waitcnt lgkmcnt(0)" ::: "memory");
      __builtin_amdgcn_s_barrier();
      __builtin_amdgcn_sched_barrier(0);
    }
  }

  // ---- epilogue 1: tanh + Vw-weighted reduce over u ----
  float sacc[2][4];
  #pragma unroll
  for (int mi = 0; mi < 2; ++mi)
    #pragma unroll
    for (int r = 0; r < 4; ++r) sacc[mi][r] = 0.0f;
  #pragma unroll
  for (int ni = 0; ni < 4; ++ni) {
    int u = (w * 4 + ni) * 16 + lr;
    float qpv = qp[b * U_ + u], vv = Vw[u];
    #pragma unroll
    for (int mi = 0; mi < 2; ++mi)
      #pragma unroll
      for (int r = 0; r < 4; ++r)
        sacc[mi][r] += tanh_fast(acc[mi][ni][r] + qpv) * vv;
  }
  #pragma unroll
  for (int mi = 0; mi < 2; ++mi)
    #pragma unroll
    for (int r = 0; r < 4; ++r) {
      float v = sacc[mi][r];
      v += __shfl_xor(v, 1); v += __shfl_xor(v, 2);
      v += __shfl_xor(v, 4); v += __shfl_xor(v, 8);
      if (lr == 0) sred[w][mi * 16 + lq * 4 + r] = v;
    }
  __syncthreads();

  // ---- epilogue 2: raw scores + p = exp(s - C) ----
  if (tid < 32) {
    float s = 0.f;
    #pragma unroll
    for (int wv = 0; wv < 8; ++wv) s += sred[wv][tid];
    score[m0 + tid] = s;                    // raw score (kB normalizes in place)
    ps2[tid] = __expf(s - C);
  }
  __syncthreads();

  // ---- epilogue 3: unnormalized context from L2-warm values rows ----
  float accc = 0.f;
  const int col = tid;                      // 512 threads <-> 512 cols
  #pragma unroll 4
  for (int row = 0; row < 32; ++row)
    accc += ps2[row] * values[(size_t)(m0 + row) * D_ + col];
  atomicAdd(&ctxU[(size_t)b * D_ + col], accc);
}

// ---------- kB: normalize (replaces softmax + ctx kernels) ----------
__global__ void kB_final(const float* __restrict__ Vw, float* __restrict__ attn,
                         float* __restrict__ ctx) {
  __shared__ float Cs;
  __shared__ float red[4];
  const int b = blockIdx.x, tid = threadIdx.x;  // 32 blocks x 256
  wave0_sumabs_vw(Vw, &Cs, tid);
  __syncthreads();
  const float C = Cs;
  float* s = attn + b * T_;
  float p[8];
  float sum = 0.f;
  #pragma unroll
  for (int i = 0; i < 8; ++i) { p[i] = __expf(s[tid + i * 256] - C); sum += p[i]; }
  #pragma unroll
  for (int off = 1; off < 64; off <<= 1) sum += __shfl_xor(sum, off);
  if ((tid & 63) == 0) red[tid >> 6] = sum;
  __syncthreads();
  sum = (red[0] + red[1]) + (red[2] + red[3]);
  const float inv = 1.0f / sum;
  #pragma unroll
  for (int i = 0; i < 8; ++i) attn[b * T_ + tid + i * 256] = p[i] * inv;
  #pragma unroll
  for (int i = 0; i < 2; ++i) ctx[b * D_ + tid + i * 256] *= inv;
}

extern "C" void kernel_launch(void* const* d_in, const int* in_sizes, int n_in,
                              void* d_out, int out_size, void* d_ws, size_t ws_size,
                              hipStream_t stream) {
  const float* query = (const float*)d_in[0];
  const float* values = (const float*)d_in[1];
  const float* W1w = (const float*)d_in[2];
  const float* W1b = (const float*)d_in[3];
  const float* W2w = (const float*)d_in[4];
  const float* W2b = (const float*)d_in[5];
  const float* Vw  = (const float*)d_in[6];
  // V_b (d_in[7]) is a constant shift under softmax -> dropped.

  float* out = (float*)d_out;
  float* ctx  = out;                 // [B, D]: holds unnormalized ctx until kB scales in place
  float* attn = out + B_ * D_;       // [B, T, 1]: holds raw scores until kB softmaxes in place
  float* score = attn;

  char* ws = (char*)d_ws;            // needs 576 KB (unchanged)
  unsigned* W2P = (unsigned*)ws;                             // 512 KB packed bf16 B
  float* qp    = (float*)(ws + 512 * 1024);                  // 64 KB

  kA_prep<<<80, 256, 0, stream>>>(W2w, W2P, query, W1w, W1b, W2b, qp, ctx);
  k2attn<<<2048, 512, 0, stream>>>(values, (const unsigned short*)W2P, qp, Vw, score, ctx);
  kB_final<<<32, 256, 0, stream>>>(Vw, attn, ctx);
}